// Round 1
// baseline (1926.551 us; speedup 1.0000x reference)
//
#include <hip/hip_runtime.h>
#include <hip/hip_bf16.h>

#define Tn 1024
#define Bn 64
#define En 128
#define G4 512
#define NEGV -10000.0f

// ---------- bf16 helpers ----------
__device__ __forceinline__ float bf2f(unsigned short u) {
    unsigned int v = ((unsigned int)u) << 16;
    float f;
    __builtin_memcpy(&f, &v, 4);
    return f;
}
__device__ __forceinline__ unsigned short f2bf(float f) {
    unsigned int u;
    __builtin_memcpy(&u, &f, 4);
    u = (u + 0x7fffu + ((u >> 16) & 1u)) >> 16;
    return (unsigned short)u;
}

// =====================================================================
// K1: input projection. G[d][t][b][g] = embed[tok(b,t)] . w_ih[g] + b_ih[g] + b_hh[g]
// GEMM: M=65536 rows (r = t*64+b), N=512, K=128. Tile 128x128, 8x8/thread.
// =====================================================================
__global__ __launch_bounds__(256) void k_inproj(
    const int* __restrict__ sent, const float* __restrict__ embed,
    const float* __restrict__ w_ih_f, const float* __restrict__ b_ih_f, const float* __restrict__ b_hh_f,
    const float* __restrict__ w_ih_b, const float* __restrict__ b_ih_b, const float* __restrict__ b_hh_b,
    unsigned short* __restrict__ G_f, unsigned short* __restrict__ G_b)
{
    __shared__ float Ald[64][128];   // [k'][row]
    __shared__ float Bld[64][128];   // [k'][gate]
    const int tid = threadIdx.x;
    const int dir = blockIdx.z;
    const float* w_ih = dir ? w_ih_b : w_ih_f;
    const float* bi   = dir ? b_ih_b : b_ih_f;
    const float* bh   = dir ? b_hh_b : b_hh_f;
    unsigned short* Gout = dir ? G_b : G_f;

    const int mt = blockIdx.x, nt = blockIdx.y;
    const int r0 = mt * 128, n0 = nt * 128;
    const int tx = tid & 15, ty = tid >> 4;

    // staging assignment: 2 threads per row, 32 k-values each
    const int sr = tid >> 1;
    const int kh = (tid & 1) * 32;
    const int rg = r0 + sr;
    const int tt = rg >> 6, bb = rg & 63;
    const int tok = sent[bb * Tn + tt];
    const float* arow = embed + (size_t)tok * En;
    const float* brow = w_ih + (size_t)(n0 + sr) * En;

    float acc[8][8];
#pragma unroll
    for (int i = 0; i < 8; ++i)
#pragma unroll
        for (int j = 0; j < 8; ++j) acc[i][j] = 0.0f;

    for (int kc = 0; kc < 2; ++kc) {
        const int kb = kc * 64 + kh;
#pragma unroll
        for (int s = 0; s < 32; s += 4) {
            float4 av = *(const float4*)(arow + kb + s);
            Ald[kh + s + 0][sr] = av.x; Ald[kh + s + 1][sr] = av.y;
            Ald[kh + s + 2][sr] = av.z; Ald[kh + s + 3][sr] = av.w;
            float4 bv = *(const float4*)(brow + kb + s);
            Bld[kh + s + 0][sr] = bv.x; Bld[kh + s + 1][sr] = bv.y;
            Bld[kh + s + 2][sr] = bv.z; Bld[kh + s + 3][sr] = bv.w;
        }
        __syncthreads();
#pragma unroll 4
        for (int k = 0; k < 64; ++k) {
            float a[8], bv[8];
            *(float4*)&a[0]  = *(const float4*)&Ald[k][ty * 8];
            *(float4*)&a[4]  = *(const float4*)&Ald[k][ty * 8 + 4];
            *(float4*)&bv[0] = *(const float4*)&Bld[k][tx * 8];
            *(float4*)&bv[4] = *(const float4*)&Bld[k][tx * 8 + 4];
#pragma unroll
            for (int i = 0; i < 8; ++i)
#pragma unroll
                for (int j = 0; j < 8; ++j) acc[i][j] += a[i] * bv[j];
        }
        __syncthreads();
    }

    float bias[8];
#pragma unroll
    for (int j = 0; j < 8; ++j) {
        int g = n0 + tx * 8 + j;
        bias[j] = bi[g] + bh[g];
    }
#pragma unroll
    for (int i = 0; i < 8; ++i) {
        int r = r0 + ty * 8 + i;
        int t = r >> 6, b2 = r & 63;
        unsigned int p0 = (unsigned int)f2bf(acc[i][0] + bias[0]) | ((unsigned int)f2bf(acc[i][1] + bias[1]) << 16);
        unsigned int p1 = (unsigned int)f2bf(acc[i][2] + bias[2]) | ((unsigned int)f2bf(acc[i][3] + bias[3]) << 16);
        unsigned int p2 = (unsigned int)f2bf(acc[i][4] + bias[4]) | ((unsigned int)f2bf(acc[i][5] + bias[5]) << 16);
        unsigned int p3 = (unsigned int)f2bf(acc[i][6] + bias[6]) | ((unsigned int)f2bf(acc[i][7] + bias[7]) << 16);
        uint4 v; v.x = p0; v.y = p1; v.z = p2; v.w = p3;
        *((uint4*)(Gout + (((size_t)t * Bn + b2) << 9) + n0 + tx * 8)) = v;
    }
}

// =====================================================================
// K2: LSTM recurrence. One workgroup per (batch, dir). 512 threads, thread g
// owns gate row g with w_hh[g][0:128] in VGPRs. h broadcast via LDS.
// =====================================================================
__global__ __launch_bounds__(512) void k_lstm(
    const float* __restrict__ whh_f, const float* __restrict__ whh_b,
    const unsigned short* __restrict__ G_f, const unsigned short* __restrict__ G_b,
    unsigned short* __restrict__ h_f, unsigned short* __restrict__ h_b)
{
    const int g = threadIdx.x;
    const int b = blockIdx.x;
    const int dir = blockIdx.y;
    const float* whh = dir ? whh_b : whh_f;
    const unsigned short* G = dir ? G_b : G_f;
    unsigned short* ho = dir ? h_b : h_f;

    __shared__ __align__(16) float hld[128];
    __shared__ float gld[512];

    float w[128];
    const float* wr = whh + (size_t)g * 128;
#pragma unroll
    for (int k = 0; k < 128; k += 4) {
        float4 v = *(const float4*)(wr + k);
        w[k] = v.x; w[k + 1] = v.y; w[k + 2] = v.z; w[k + 3] = v.w;
    }
    if (g < 128) hld[g] = 0.0f;
    float c = 0.0f;
    __syncthreads();

    int t = dir ? (Tn - 1) : 0;
    const int dt = dir ? -1 : 1;
    unsigned short gc = G[(((size_t)t * Bn + b) << 9) + g];

    for (int s = 0; s < Tn; ++s) {
        const int tn = t + dt;
        unsigned short gn = 0;
        if (s + 1 < Tn) gn = G[(((size_t)tn * Bn + b) << 9) + g];   // prefetch next step

        float a0 = bf2f(gc), a1 = 0.0f, a2 = 0.0f, a3 = 0.0f;
#pragma unroll
        for (int k = 0; k < 128; k += 4) {
            float4 h4 = *(const float4*)&hld[k];
            a0 += w[k] * h4.x; a1 += w[k + 1] * h4.y;
            a2 += w[k + 2] * h4.z; a3 += w[k + 3] * h4.w;
        }
        gld[g] = (a0 + a1) + (a2 + a3);
        __syncthreads();

        if (g < 128) {
            float iv = gld[g], fv = gld[128 + g], gv = gld[256 + g], ov = gld[384 + g];
            float si = 1.0f / (1.0f + __expf(-iv));
            float sf = 1.0f / (1.0f + __expf(-fv));
            float so = 1.0f / (1.0f + __expf(-ov));
            float tg = 1.0f - 2.0f / (1.0f + __expf(2.0f * gv));   // tanh
            c = sf * c + si * tg;
            float th = 1.0f - 2.0f / (1.0f + __expf(2.0f * c));
            float hn = so * th;
            hld[g] = hn;
            ho[(((size_t)t * Bn + b) << 7) + g] = f2bf(hn);
        }
        __syncthreads();
        gc = gn; t = tn;
    }
}

// =====================================================================
// K3: feats[t][b][k] = h_f[t,b,:].w_out[k][0:128] + h_b[t,b,:].w_out[k][128:256] + b_out[k]
// One thread per row (t*64+b); w_out transposed+padded in LDS.
// =====================================================================
__global__ __launch_bounds__(256) void k_feats(
    const unsigned short* __restrict__ h_f, const unsigned short* __restrict__ h_b,
    const float* __restrict__ w_out, const float* __restrict__ b_out,
    float* __restrict__ feats)
{
    __shared__ float wl[256][12];   // [j][k], k padded to 12
    __shared__ float bl[12];
    const int tid = threadIdx.x;
#pragma unroll
    for (int s = 0; s < 9; ++s) wl[tid][s] = w_out[s * 256 + tid];
#pragma unroll
    for (int s = 9; s < 12; ++s) wl[tid][s] = 0.0f;
    if (tid < 12) bl[tid] = (tid < 9) ? b_out[tid] : 0.0f;
    __syncthreads();

    const int r = blockIdx.x * 256 + tid;
    const unsigned short* hfr = h_f + (size_t)r * 128;
    const unsigned short* hbr = h_b + (size_t)r * 128;
    float acc[12];
#pragma unroll
    for (int k = 0; k < 12; ++k) acc[k] = bl[k];

    for (int ch = 0; ch < 32; ++ch) {
        const unsigned short* src = (ch < 16) ? (hfr + ch * 8) : (hbr + (ch - 16) * 8);
        uint4 hv = *(const uint4*)src;
        unsigned int hw0 = hv.x, hw1 = hv.y, hw2 = hv.z, hw3 = hv.w;
        const int jb = ch * 8;
#pragma unroll
        for (int q = 0; q < 8; ++q) {
            unsigned int word = (q < 2) ? hw0 : ((q < 4) ? hw1 : ((q < 6) ? hw2 : hw3));
            unsigned short hs = (q & 1) ? (unsigned short)(word >> 16) : (unsigned short)(word & 0xffff);
            float hf = bf2f(hs);
            const float* wrp = &wl[jb + q][0];
            float4 w0 = *(const float4*)(wrp);
            float4 w1 = *(const float4*)(wrp + 4);
            float4 w2 = *(const float4*)(wrp + 8);
            acc[0] += hf * w0.x; acc[1] += hf * w0.y; acc[2] += hf * w0.z; acc[3] += hf * w0.w;
            acc[4] += hf * w1.x; acc[5] += hf * w1.y; acc[6] += hf * w1.z; acc[7] += hf * w1.w;
            acc[8] += hf * w2.x; acc[9] += hf * w2.y; acc[10] += hf * w2.z; acc[11] += hf * w2.w;
        }
    }
    float* fr = feats + (size_t)r * 9;
#pragma unroll
    for (int k = 0; k < 9; ++k) fr[k] = acc[k];
}

// =====================================================================
// K4: Viterbi DP + backtrace. One wave (64 threads) per batch, wave-synchronous.
// bp rows padded to 16B so the backtrace load address is tag-independent.
// =====================================================================
__global__ __launch_bounds__(64) void k_viterbi(
    const float* __restrict__ feats, const float* __restrict__ trans,
    float* __restrict__ out)
{
    __shared__ __align__(16) unsigned char bp[1024 * 16];   // 16 KB
    __shared__ float fl[1024 * 9];                          // 36 KB
    __shared__ float dl[12];
    __shared__ unsigned char pt[1024];

    const int b = blockIdx.x, tid = threadIdx.x;

    // preload this batch's feats into LDS
    for (int i = tid; i < 9216; i += 64) {
        int t = i / 9;
        int n = i - t * 9;
        fl[i] = feats[((size_t)t * 64 + b) * 9 + n];
    }

    float tr[9];
    float trs = -3.0e38f;
    if (tid < 9) {
#pragma unroll
        for (int p = 0; p < 9; ++p) tr[p] = trans[tid * 9 + p];
        trs = trans[8 * 9 + tid];
    }
    if (tid < 12) dl[tid] = (tid == 7) ? 0.0f : NEGV;
    __syncthreads();

    if (tid < 9) {
        for (int t = 0; t < 1024; ++t) {
            float4 d0 = *(const float4*)&dl[0];
            float4 d1 = *(const float4*)&dl[4];
            float d8 = dl[8];
            float dv0 = d0.x, dv1 = d0.y, dv2 = d0.z, dv3 = d0.w;
            float dv4 = d1.x, dv5 = d1.y, dv6 = d1.z, dv7 = d1.w;
            float m = dv0 + tr[0]; int am = 0;
            float v;
            v = dv1 + tr[1]; if (v > m) { m = v; am = 1; }
            v = dv2 + tr[2]; if (v > m) { m = v; am = 2; }
            v = dv3 + tr[3]; if (v > m) { m = v; am = 3; }
            v = dv4 + tr[4]; if (v > m) { m = v; am = 4; }
            v = dv5 + tr[5]; if (v > m) { m = v; am = 5; }
            v = dv6 + tr[6]; if (v > m) { m = v; am = 6; }
            v = dv7 + tr[7]; if (v > m) { m = v; am = 7; }
            v = d8  + tr[8]; if (v > m) { m = v; am = 8; }
            float nd = m + fl[t * 9 + tid];
            dl[tid] = nd;
            bp[t * 16 + tid] = (unsigned char)am;
        }
    }
    // terminal: tv = delta[n] + trans[STOP][n]
    float tv = (tid < 9) ? (dl[tid] + trs) : -3.0e38f;
    int bi = tid;
#pragma unroll
    for (int off = 8; off >= 1; off >>= 1) {
        float ov = __shfl_down(tv, off, 64);
        int oi = __shfl_down(bi, off, 64);
        if (ov > tv || (ov == tv && oi < bi)) { tv = ov; bi = oi; }
    }
    int best = __shfl(bi, 0, 64);
    if (tid == 0) out[b] = tv;

    if (tid == 0) {
        int tag = best;
        for (int t0 = 1023; t0 >= 0; t0 -= 8) {
            uint4 rows[8];
#pragma unroll
            for (int i = 0; i < 8; ++i) rows[i] = *(const uint4*)&bp[(t0 - i) * 16];
#pragma unroll
            for (int i = 0; i < 8; ++i) {
                pt[t0 - i] = (unsigned char)tag;
                uint4 rw = rows[i];
                unsigned int sel = (unsigned int)tag >> 2;
                unsigned int word = (sel == 0) ? rw.x : ((sel == 1) ? rw.y : rw.z);
                tag = (int)((word >> ((tag & 3) * 8)) & 0xffu);
            }
        }
    }
    // coalesced path write (as float values)
    for (int i = tid; i < 1024; i += 64) {
        out[64 + b * 1024 + i] = (float)pt[i];
    }
}

// =====================================================================
extern "C" void kernel_launch(void* const* d_in, const int* in_sizes, int n_in,
                              void* d_out, int out_size, void* d_ws, size_t ws_size,
                              hipStream_t stream) {
    const int*   sent   = (const int*)d_in[0];
    const float* embed  = (const float*)d_in[1];
    const float* w_ih_f = (const float*)d_in[2];
    const float* w_hh_f = (const float*)d_in[3];
    const float* b_ih_f = (const float*)d_in[4];
    const float* b_hh_f = (const float*)d_in[5];
    const float* w_ih_b = (const float*)d_in[6];
    const float* w_hh_b = (const float*)d_in[7];
    const float* b_ih_b = (const float*)d_in[8];
    const float* b_hh_b = (const float*)d_in[9];
    const float* w_out  = (const float*)d_in[10];
    const float* b_out  = (const float*)d_in[11];
    const float* trans  = (const float*)d_in[12];
    float* out = (float*)d_out;

    // workspace layout (bf16 G + h, fp32 feats): ~162.4 MB
    unsigned short* G_f = (unsigned short*)d_ws;
    unsigned short* G_b = G_f + (size_t)Tn * Bn * G4;      // +33.5M elems
    unsigned short* h_f = G_b + (size_t)Tn * Bn * G4;
    unsigned short* h_b = h_f + (size_t)Tn * Bn * 128;
    float* feats = (float*)(h_b + (size_t)Tn * Bn * 128);

    k_inproj<<<dim3(512, 4, 2), 256, 0, stream>>>(sent, embed,
        w_ih_f, b_ih_f, b_hh_f, w_ih_b, b_ih_b, b_hh_b, G_f, G_b);
    k_lstm<<<dim3(64, 2), 512, 0, stream>>>(w_hh_f, w_hh_b, G_f, G_b, h_f, h_b);
    k_feats<<<256, 256, 0, stream>>>(h_f, h_b, w_out, b_out, feats);
    k_viterbi<<<64, 64, 0, stream>>>(feats, trans, out);
}

// Round 2
// 1530.391 us; speedup vs baseline: 1.2589x; 1.2589x over previous
//
#include <hip/hip_runtime.h>
#include <hip/hip_bf16.h>

#define Tn 1024
#define Bn 64
#define En 128
#define G4 512
#define NEGV -10000.0f

// ---------- bf16 helpers ----------
__device__ __forceinline__ float bf2f(unsigned short u) {
    unsigned int v = ((unsigned int)u) << 16;
    float f;
    __builtin_memcpy(&f, &v, 4);
    return f;
}
__device__ __forceinline__ unsigned short f2bf(float f) {
    unsigned int u;
    __builtin_memcpy(&u, &f, 4);
    u = (u + 0x7fffu + ((u >> 16) & 1u)) >> 16;
    return (unsigned short)u;
}

// =====================================================================
// K1: input projection. G[d][t][b][g] = embed[tok(b,t)] . w_ih[g] + b_ih[g] + b_hh[g]
// GEMM: M=65536 rows (r = t*64+b), N=512, K=128. Tile 128x128, 8x8/thread.
// =====================================================================
__global__ __launch_bounds__(256) void k_inproj(
    const int* __restrict__ sent, const float* __restrict__ embed,
    const float* __restrict__ w_ih_f, const float* __restrict__ b_ih_f, const float* __restrict__ b_hh_f,
    const float* __restrict__ w_ih_b, const float* __restrict__ b_ih_b, const float* __restrict__ b_hh_b,
    unsigned short* __restrict__ G_f, unsigned short* __restrict__ G_b)
{
    __shared__ float Ald[64][128];   // [k'][row]
    __shared__ float Bld[64][128];   // [k'][gate]
    const int tid = threadIdx.x;
    const int dir = blockIdx.z;
    const float* w_ih = dir ? w_ih_b : w_ih_f;
    const float* bi   = dir ? b_ih_b : b_ih_f;
    const float* bh   = dir ? b_hh_b : b_hh_f;
    unsigned short* Gout = dir ? G_b : G_f;

    const int mt = blockIdx.x, nt = blockIdx.y;
    const int r0 = mt * 128, n0 = nt * 128;
    const int tx = tid & 15, ty = tid >> 4;

    // staging assignment: 2 threads per row, 32 k-values each
    const int sr = tid >> 1;
    const int kh = (tid & 1) * 32;
    const int rg = r0 + sr;
    const int tt = rg >> 6, bb = rg & 63;
    const int tok = sent[bb * Tn + tt];
    const float* arow = embed + (size_t)tok * En;
    const float* brow = w_ih + (size_t)(n0 + sr) * En;

    float acc[8][8];
#pragma unroll
    for (int i = 0; i < 8; ++i)
#pragma unroll
        for (int j = 0; j < 8; ++j) acc[i][j] = 0.0f;

    for (int kc = 0; kc < 2; ++kc) {
        const int kb = kc * 64 + kh;
#pragma unroll
        for (int s = 0; s < 32; s += 4) {
            float4 av = *(const float4*)(arow + kb + s);
            Ald[kh + s + 0][sr] = av.x; Ald[kh + s + 1][sr] = av.y;
            Ald[kh + s + 2][sr] = av.z; Ald[kh + s + 3][sr] = av.w;
            float4 bv = *(const float4*)(brow + kb + s);
            Bld[kh + s + 0][sr] = bv.x; Bld[kh + s + 1][sr] = bv.y;
            Bld[kh + s + 2][sr] = bv.z; Bld[kh + s + 3][sr] = bv.w;
        }
        __syncthreads();
#pragma unroll 4
        for (int k = 0; k < 64; ++k) {
            float a[8], bv[8];
            *(float4*)&a[0]  = *(const float4*)&Ald[k][ty * 8];
            *(float4*)&a[4]  = *(const float4*)&Ald[k][ty * 8 + 4];
            *(float4*)&bv[0] = *(const float4*)&Bld[k][tx * 8];
            *(float4*)&bv[4] = *(const float4*)&Bld[k][tx * 8 + 4];
#pragma unroll
            for (int i = 0; i < 8; ++i)
#pragma unroll
                for (int j = 0; j < 8; ++j) acc[i][j] += a[i] * bv[j];
        }
        __syncthreads();
    }

    float bias[8];
#pragma unroll
    for (int j = 0; j < 8; ++j) {
        int g = n0 + tx * 8 + j;
        bias[j] = bi[g] + bh[g];
    }
#pragma unroll
    for (int i = 0; i < 8; ++i) {
        int r = r0 + ty * 8 + i;
        int t = r >> 6, b2 = r & 63;
        unsigned int p0 = (unsigned int)f2bf(acc[i][0] + bias[0]) | ((unsigned int)f2bf(acc[i][1] + bias[1]) << 16);
        unsigned int p1 = (unsigned int)f2bf(acc[i][2] + bias[2]) | ((unsigned int)f2bf(acc[i][3] + bias[3]) << 16);
        unsigned int p2 = (unsigned int)f2bf(acc[i][4] + bias[4]) | ((unsigned int)f2bf(acc[i][5] + bias[5]) << 16);
        unsigned int p3 = (unsigned int)f2bf(acc[i][6] + bias[6]) | ((unsigned int)f2bf(acc[i][7] + bias[7]) << 16);
        uint4 v; v.x = p0; v.y = p1; v.z = p2; v.w = p3;
        *((uint4*)(Gout + (((size_t)t * Bn + b2) << 9) + n0 + tx * 8)) = v;
    }
}

// =====================================================================
// K2: LSTM recurrence. One workgroup per (batch, dir). 512 threads.
// Thread (j = tid>>2, q = tid&3) owns gate row q*128+j; the 4 gates of
// h-index j sit in adjacent lanes of one wave -> combine via __shfl.
// Double-buffered h in LDS -> ONE barrier per step.
// __launch_bounds__(512,2): allow 256 VGPRs so w row stays register-resident.
// =====================================================================
__global__ __launch_bounds__(512, 2) void k_lstm(
    const float* __restrict__ whh_f, const float* __restrict__ whh_b,
    const unsigned short* __restrict__ G_f, const unsigned short* __restrict__ G_b,
    unsigned short* __restrict__ h_f, unsigned short* __restrict__ h_b)
{
    const int tid = threadIdx.x;
    const int j = tid >> 2;        // h index 0..127
    const int q = tid & 3;         // gate: 0=i, 1=f, 2=g, 3=o (torch order)
    const int b = blockIdx.x;
    const int dir = blockIdx.y;
    const float* whh = dir ? whh_b : whh_f;
    const unsigned short* G = dir ? G_b : G_f;
    unsigned short* ho = dir ? h_b : h_f;

    __shared__ __align__(16) float hbuf[2][128];

    const int row = q * 128 + j;
    const float* wr = whh + (size_t)row * 128;
    float4 w4[32];
#pragma unroll
    for (int k = 0; k < 32; ++k) w4[k] = ((const float4*)wr)[k];

    if (tid < 128) hbuf[0][tid] = 0.0f;
    float c = 0.0f;
    __syncthreads();

    int t = dir ? (Tn - 1) : 0;
    const int dt = dir ? -1 : 1;
    unsigned short gc = G[(((size_t)t * Bn + b) << 9) + row];

    const int lbase = (tid & 63) & ~3;   // quad base lane within wave
    int p = 0;
    for (int s = 0; s < Tn; ++s) {
        const int tn = t + dt;
        unsigned short gn = 0;
        if (s + 1 < Tn) gn = G[(((size_t)tn * Bn + b) << 9) + row];   // prefetch

        float a0 = bf2f(gc), a1 = 0.0f, a2 = 0.0f, a3 = 0.0f;
        const float4* hb = (const float4*)&hbuf[p][0];
#pragma unroll
        for (int k = 0; k < 32; ++k) {
            float4 h4 = hb[k];
            float4 w = w4[k];
            a0 += w.x * h4.x; a1 += w.y * h4.y;
            a2 += w.z * h4.z; a3 += w.w * h4.w;
        }
        float dot = (a0 + a1) + (a2 + a3);

        // gather the quad's 4 gate dots into the q==0 lane
        float vi = __shfl(dot, lbase + 0, 64);
        float vf = __shfl(dot, lbase + 1, 64);
        float vg = __shfl(dot, lbase + 2, 64);
        float vo = __shfl(dot, lbase + 3, 64);

        if (q == 0) {
            float si = 1.0f / (1.0f + __expf(-vi));
            float sf = 1.0f / (1.0f + __expf(-vf));
            float so = 1.0f / (1.0f + __expf(-vo));
            float tg = 1.0f - 2.0f / (1.0f + __expf(2.0f * vg));   // tanh
            c = sf * c + si * tg;
            float th = 1.0f - 2.0f / (1.0f + __expf(2.0f * c));
            float hn = so * th;
            hbuf[1 - p][j] = hn;
            ho[(((size_t)t * Bn + b) << 7) + j] = f2bf(hn);
        }
        __syncthreads();
        gc = gn; t = tn; p ^= 1;
    }
}

// =====================================================================
// K3: feats[t][b][k] = h_f[t,b,:].w_out[k][0:128] + h_b[t,b,:].w_out[k][128:256] + b_out[k]
// One thread per row (t*64+b); w_out transposed+padded in LDS.
// =====================================================================
__global__ __launch_bounds__(256) void k_feats(
    const unsigned short* __restrict__ h_f, const unsigned short* __restrict__ h_b,
    const float* __restrict__ w_out, const float* __restrict__ b_out,
    float* __restrict__ feats)
{
    __shared__ float wl[256][12];   // [j][k], k padded to 12
    __shared__ float bl[12];
    const int tid = threadIdx.x;
#pragma unroll
    for (int s = 0; s < 9; ++s) wl[tid][s] = w_out[s * 256 + tid];
#pragma unroll
    for (int s = 9; s < 12; ++s) wl[tid][s] = 0.0f;
    if (tid < 12) bl[tid] = (tid < 9) ? b_out[tid] : 0.0f;
    __syncthreads();

    const int r = blockIdx.x * 256 + tid;
    const unsigned short* hfr = h_f + (size_t)r * 128;
    const unsigned short* hbr = h_b + (size_t)r * 128;
    float acc[12];
#pragma unroll
    for (int k = 0; k < 12; ++k) acc[k] = bl[k];

    for (int ch = 0; ch < 32; ++ch) {
        const unsigned short* src = (ch < 16) ? (hfr + ch * 8) : (hbr + (ch - 16) * 8);
        uint4 hv = *(const uint4*)src;
        unsigned int hw0 = hv.x, hw1 = hv.y, hw2 = hv.z, hw3 = hv.w;
        const int jb = ch * 8;
#pragma unroll
        for (int q = 0; q < 8; ++q) {
            unsigned int word = (q < 2) ? hw0 : ((q < 4) ? hw1 : ((q < 6) ? hw2 : hw3));
            unsigned short hs = (q & 1) ? (unsigned short)(word >> 16) : (unsigned short)(word & 0xffff);
            float hf = bf2f(hs);
            const float* wrp = &wl[jb + q][0];
            float4 w0 = *(const float4*)(wrp);
            float4 w1 = *(const float4*)(wrp + 4);
            float4 w2 = *(const float4*)(wrp + 8);
            acc[0] += hf * w0.x; acc[1] += hf * w0.y; acc[2] += hf * w0.z; acc[3] += hf * w0.w;
            acc[4] += hf * w1.x; acc[5] += hf * w1.y; acc[6] += hf * w1.z; acc[7] += hf * w1.w;
            acc[8] += hf * w2.x; acc[9] += hf * w2.y; acc[10] += hf * w2.z; acc[11] += hf * w2.w;
        }
    }
    float* fr = feats + (size_t)r * 9;
#pragma unroll
    for (int k = 0; k < 9; ++k) fr[k] = acc[k];
}

// =====================================================================
// K4: Viterbi DP + backtrace. One wave (64 threads) per batch, wave-synchronous.
// bp rows padded to 16B so the backtrace load address is tag-independent.
// =====================================================================
__global__ __launch_bounds__(64) void k_viterbi(
    const float* __restrict__ feats, const float* __restrict__ trans,
    float* __restrict__ out)
{
    __shared__ __align__(16) unsigned char bp[1024 * 16];   // 16 KB
    __shared__ float fl[1024 * 9];                          // 36 KB
    __shared__ float dl[12];
    __shared__ unsigned char pt[1024];

    const int b = blockIdx.x, tid = threadIdx.x;

    // preload this batch's feats into LDS
    for (int i = tid; i < 9216; i += 64) {
        int t = i / 9;
        int n = i - t * 9;
        fl[i] = feats[((size_t)t * 64 + b) * 9 + n];
    }

    float tr[9];
    float trs = -3.0e38f;
    if (tid < 9) {
#pragma unroll
        for (int p = 0; p < 9; ++p) tr[p] = trans[tid * 9 + p];
        trs = trans[8 * 9 + tid];
    }
    if (tid < 12) dl[tid] = (tid == 7) ? 0.0f : NEGV;
    __syncthreads();

    if (tid < 9) {
        for (int t = 0; t < 1024; ++t) {
            float4 d0 = *(const float4*)&dl[0];
            float4 d1 = *(const float4*)&dl[4];
            float d8 = dl[8];
            float dv0 = d0.x, dv1 = d0.y, dv2 = d0.z, dv3 = d0.w;
            float dv4 = d1.x, dv5 = d1.y, dv6 = d1.z, dv7 = d1.w;
            float m = dv0 + tr[0]; int am = 0;
            float v;
            v = dv1 + tr[1]; if (v > m) { m = v; am = 1; }
            v = dv2 + tr[2]; if (v > m) { m = v; am = 2; }
            v = dv3 + tr[3]; if (v > m) { m = v; am = 3; }
            v = dv4 + tr[4]; if (v > m) { m = v; am = 4; }
            v = dv5 + tr[5]; if (v > m) { m = v; am = 5; }
            v = dv6 + tr[6]; if (v > m) { m = v; am = 6; }
            v = dv7 + tr[7]; if (v > m) { m = v; am = 7; }
            v = d8  + tr[8]; if (v > m) { m = v; am = 8; }
            float nd = m + fl[t * 9 + tid];
            dl[tid] = nd;
            bp[t * 16 + tid] = (unsigned char)am;
        }
    }
    // terminal: tv = delta[n] + trans[STOP][n]
    float tv = (tid < 9) ? (dl[tid] + trs) : -3.0e38f;
    int bi = tid;
#pragma unroll
    for (int off = 8; off >= 1; off >>= 1) {
        float ov = __shfl_down(tv, off, 64);
        int oi = __shfl_down(bi, off, 64);
        if (ov > tv || (ov == tv && oi < bi)) { tv = ov; bi = oi; }
    }
    int best = __shfl(bi, 0, 64);
    if (tid == 0) out[b] = tv;

    if (tid == 0) {
        int tag = best;
        for (int t0 = 1023; t0 >= 0; t0 -= 8) {
            uint4 rows[8];
#pragma unroll
            for (int i = 0; i < 8; ++i) rows[i] = *(const uint4*)&bp[(t0 - i) * 16];
#pragma unroll
            for (int i = 0; i < 8; ++i) {
                pt[t0 - i] = (unsigned char)tag;
                uint4 rw = rows[i];
                unsigned int sel = (unsigned int)tag >> 2;
                unsigned int word = (sel == 0) ? rw.x : ((sel == 1) ? rw.y : rw.z);
                tag = (int)((word >> ((tag & 3) * 8)) & 0xffu);
            }
        }
    }
    // coalesced path write (as float values)
    for (int i = tid; i < 1024; i += 64) {
        out[64 + b * 1024 + i] = (float)pt[i];
    }
}

// =====================================================================
extern "C" void kernel_launch(void* const* d_in, const int* in_sizes, int n_in,
                              void* d_out, int out_size, void* d_ws, size_t ws_size,
                              hipStream_t stream) {
    const int*   sent   = (const int*)d_in[0];
    const float* embed  = (const float*)d_in[1];
    const float* w_ih_f = (const float*)d_in[2];
    const float* w_hh_f = (const float*)d_in[3];
    const float* b_ih_f = (const float*)d_in[4];
    const float* b_hh_f = (const float*)d_in[5];
    const float* w_ih_b = (const float*)d_in[6];
    const float* w_hh_b = (const float*)d_in[7];
    const float* b_ih_b = (const float*)d_in[8];
    const float* b_hh_b = (const float*)d_in[9];
    const float* w_out  = (const float*)d_in[10];
    const float* b_out  = (const float*)d_in[11];
    const float* trans  = (const float*)d_in[12];
    float* out = (float*)d_out;

    // workspace layout (bf16 G + h, fp32 feats): ~162.4 MB
    unsigned short* G_f = (unsigned short*)d_ws;
    unsigned short* G_b = G_f + (size_t)Tn * Bn * G4;      // +33.5M elems
    unsigned short* h_f = G_b + (size_t)Tn * Bn * G4;
    unsigned short* h_b = h_f + (size_t)Tn * Bn * 128;
    float* feats = (float*)(h_b + (size_t)Tn * Bn * 128);

    k_inproj<<<dim3(512, 4, 2), 256, 0, stream>>>(sent, embed,
        w_ih_f, b_ih_f, b_hh_f, w_ih_b, b_ih_b, b_hh_b, G_f, G_b);
    k_lstm<<<dim3(64, 2), 512, 0, stream>>>(w_hh_f, w_hh_b, G_f, G_b, h_f, h_b);
    k_feats<<<256, 256, 0, stream>>>(h_f, h_b, w_out, b_out, feats);
    k_viterbi<<<64, 64, 0, stream>>>(feats, trans, out);
}